// Round 2
// baseline (1887.997 us; speedup 1.0000x reference)
//
#include <hip/hip_runtime.h>

// ---------------------------------------------------------------------------
// SAGE_Re GNN forward: 5 layers over N=100000 nodes, E=800000 edges.
// CSR built per call (no float atomics); wave-per-node gather aggregation;
// fp32 LDS-tiled GEMM (64xBN tile, BK=16) with fused bias/ReLU/ReZero epilogue.
// Workspace budget: 2 x (N*256 fp32) feature buffers + ~6 MB CSR  (~210 MB).
// In-place GEMM outputs (same rows, same ld) keep it to 2 buffers.
// ---------------------------------------------------------------------------

__global__ __launch_bounds__(256) void zero_int_kernel(int* __restrict__ p, int n)
{
    int i = blockIdx.x * 256 + threadIdx.x;
    if (i < n) p[i] = 0;
}

__global__ __launch_bounds__(256) void count_deg_kernel(
    const int* __restrict__ row, int* __restrict__ deg, int E)
{
    int e = blockIdx.x * 256 + threadIdx.x;
    if (e < E) atomicAdd(&deg[row[e]], 1);
}

// single-block scan: rp[0]=0, rp[i+1]=incl_sum(deg[0..i]), cursor[i]=excl_sum
__global__ __launch_bounds__(1024) void scan_kernel(
    const int* __restrict__ deg, int* __restrict__ rp,
    int* __restrict__ cursor, int n)
{
    __shared__ int wsum[16];
    int t = threadIdx.x;
    int lane = t & 63, w = t >> 6;
    if (t == 0) rp[0] = 0;
    int carry = 0;
    for (int base = 0; base < n; base += 1024) {
        int i = base + t;
        int xv = (i < n) ? deg[i] : 0;
        int s = xv;
        #pragma unroll
        for (int off = 1; off < 64; off <<= 1) {
            int v = __shfl_up(s, off, 64);
            if (lane >= off) s += v;
        }
        if (lane == 63) wsum[w] = s;
        __syncthreads();
        if (w == 0 && lane < 16) {
            int ws = wsum[lane];
            #pragma unroll
            for (int off = 1; off < 16; off <<= 1) {
                int v = __shfl_up(ws, off, 64);
                if (lane >= off) ws += v;
            }
            wsum[lane] = ws;
        }
        __syncthreads();
        int wo = (w == 0) ? 0 : wsum[w - 1];
        if (i < n) {
            int incl = carry + wo + s;
            rp[i + 1] = incl;
            cursor[i] = incl - xv;
        }
        carry += wsum[15];
        __syncthreads();
    }
}

__global__ __launch_bounds__(256) void scales_kernel(
    const int* __restrict__ deg, float* __restrict__ dinv,
    float* __restrict__ cinv, int n)
{
    int i = blockIdx.x * 256 + threadIdx.x;
    if (i >= n) return;
    int d = deg[i];
    float df = (float)d;
    dinv[i] = (d > 0) ? rsqrtf(df) : 0.0f;
    cinv[i] = 1.0f / fmaxf(df, 1.0f);
}

__global__ __launch_bounds__(256) void fill_csr_kernel(
    const int* __restrict__ row, const int* __restrict__ col,
    int* __restrict__ cursor, int* __restrict__ colS, int E)
{
    int e = blockIdx.x * 256 + threadIdx.x;
    if (e < E) {
        int p = atomicAdd(&cursor[row[e]], 1);
        colS[p] = col[e];
    }
}

// ---------------- aggregation: wave per node ----------------
// out[i,:] = nscale[i] * sum_{e in row i} escale[col[e]] * h[col[e],:]
// escale == nullptr -> 1.0.  ldh/ldo are leading dims (floats).

template <int C>
__global__ __launch_bounds__(256) void agg_csr_kernel(
    const float* __restrict__ h, int ldh,
    const int* __restrict__ rp, const int* __restrict__ cols,
    const float* __restrict__ escale, const float* __restrict__ nscale,
    float* __restrict__ out, int ldo, int n)
{
    constexpr int V = C / 64;  // floats per lane: 2 (C=128) or 4 (C=256)
    int wave = blockIdx.x * 4 + (threadIdx.x >> 6);
    int lane = threadIdx.x & 63;
    if (wave >= n) return;
    int s = rp[wave], e = rp[wave + 1];
    float acc[V];
    #pragma unroll
    for (int v = 0; v < V; ++v) acc[v] = 0.0f;
    for (int i = s; i < e; ++i) {
        int c = cols[i];
        float sc = escale ? escale[c] : 1.0f;
        const float* src = h + (size_t)c * ldh;
        if constexpr (V == 4) {
            float4 val = *(const float4*)(src + lane * 4);
            acc[0] += sc * val.x; acc[1] += sc * val.y;
            acc[2] += sc * val.z; acc[3] += sc * val.w;
        } else {
            float2 val = *(const float2*)(src + lane * 2);
            acc[0] += sc * val.x; acc[1] += sc * val.y;
        }
    }
    float ns = nscale[wave];
    float* dst = out + (size_t)wave * ldo;
    if constexpr (V == 4) {
        *(float4*)(dst + lane * 4) =
            make_float4(acc[0] * ns, acc[1] * ns, acc[2] * ns, acc[3] * ns);
    } else {
        *(float2*)(dst + lane * 2) = make_float2(acc[0] * ns, acc[1] * ns);
    }
}

// ---------------- GEMM: out[M,Nout] = epi([A1|A2] @ [B1;B2] + bias) ---------
// EPI 0: acc+bias   EPI 1: relu(acc+bias)   EPI 2: res + alpha*(acc+bias)
// Block: 64 rows x BN_T cols; 256 threads, each 4 x (BN_T/16) outputs.
// Safe to write out == A1 or A2 in-place when ld matches (reads of this
// block's rows all complete inside the K loop before the epilogue writes,
// and no other block reads these rows).

template <int BN_T, int EPI>
__global__ __launch_bounds__(256) void gemm_ep_kernel(
    const float* __restrict__ A1, int K1, int lda1,
    const float* __restrict__ A2, int K2, int lda2,
    const float* __restrict__ B1, const float* __restrict__ B2,
    const float* __restrict__ bias,
    const float* __restrict__ res,
    const float* __restrict__ alpha_ptr, int alpha_idx,
    float* __restrict__ out, int M, int Nout)
{
    constexpr int NJ = BN_T / 64;            // float4 column groups per thread
    __shared__ float As[16][68];             // transposed A tile, padded
    __shared__ float Bs[16][BN_T];
    int t = threadIdx.x;
    int tx = t & 15, ty = t >> 4;
    int m0 = blockIdx.x * 64;
    int Ktot = K1 + K2;

    int arow = t >> 2, kq = t & 3;           // A loader: 1 float4 per thread
    int kb = t >> 4, nq = t & 15;            // B loader: NJ float4 per thread

    float acc[4][NJ * 4];
    #pragma unroll
    for (int i = 0; i < 4; ++i)
        #pragma unroll
        for (int j = 0; j < NJ * 4; ++j) acc[i][j] = 0.0f;

    for (int k0 = 0; k0 < Ktot; k0 += 16) {
        const float* Asrc; const float* Bsrc; int lda, kk;
        if (k0 < K1) { Asrc = A1; lda = lda1; kk = k0;      Bsrc = B1; }
        else         { Asrc = A2; lda = lda2; kk = k0 - K1; Bsrc = B2; }
        // ---- A tile (transpose into LDS) ----
        {
            int gm = m0 + arow;
            float4 v = make_float4(0.f, 0.f, 0.f, 0.f);
            if (gm < M) v = *(const float4*)(Asrc + (size_t)gm * lda + kk + kq * 4);
            As[kq * 4 + 0][arow] = v.x;
            As[kq * 4 + 1][arow] = v.y;
            As[kq * 4 + 2][arow] = v.z;
            As[kq * 4 + 3][arow] = v.w;
        }
        // ---- B tile ----
        {
            int gk = kk + kb;
            const float* bp = Bsrc + (size_t)gk * Nout;
            #pragma unroll
            for (int j = 0; j < NJ; ++j) {
                int gn = nq * 4 + 64 * j;
                float4 v;
                if (gn + 3 < Nout) {
                    v = *(const float4*)(bp + gn);
                } else {
                    v.x = (gn + 0 < Nout) ? bp[gn + 0] : 0.f;
                    v.y = (gn + 1 < Nout) ? bp[gn + 1] : 0.f;
                    v.z = (gn + 2 < Nout) ? bp[gn + 2] : 0.f;
                    v.w = (gn + 3 < Nout) ? bp[gn + 3] : 0.f;
                }
                *(float4*)&Bs[kb][gn] = v;
            }
        }
        __syncthreads();
        #pragma unroll
        for (int k = 0; k < 16; ++k) {
            float4 a = *(const float4*)&As[k][ty * 4];
            float av[4] = {a.x, a.y, a.z, a.w};
            #pragma unroll
            for (int j = 0; j < NJ; ++j) {
                float4 b = *(const float4*)&Bs[k][tx * 4 + 64 * j];
                float bv[4] = {b.x, b.y, b.z, b.w};
                #pragma unroll
                for (int i = 0; i < 4; ++i)
                    #pragma unroll
                    for (int c = 0; c < 4; ++c)
                        acc[i][j * 4 + c] += av[i] * bv[c];
            }
        }
        __syncthreads();
    }

    float alpha = 0.f;
    if (EPI == 2) alpha = alpha_ptr[alpha_idx];
    #pragma unroll
    for (int i = 0; i < 4; ++i) {
        int m = m0 + ty * 4 + i;
        if (m >= M) continue;
        #pragma unroll
        for (int j = 0; j < NJ; ++j) {
            #pragma unroll
            for (int c = 0; c < 4; ++c) {
                int n = tx * 4 + 64 * j + c;
                if (n >= Nout) continue;
                float v = acc[i][j * 4 + c] + bias[n];
                if (EPI == 1) v = fmaxf(v, 0.f);
                if (EPI == 2) v = res[(size_t)m * Nout + n] + alpha * v;
                out[(size_t)m * Nout + n] = v;
            }
        }
    }
}

// ---------------------------------------------------------------------------

extern "C" void kernel_launch(void* const* d_in, const int* in_sizes, int n_in,
                              void* d_out, int out_size, void* d_ws, size_t ws_size,
                              hipStream_t stream)
{
    const float* x      = (const float*)d_in[0];
    const int*   ei     = (const int*)d_in[1];
    const float* alpha  = (const float*)d_in[2];
    const float* W0     = (const float*)d_in[3];
    const float* b0     = (const float*)d_in[4];
    const float* W1     = (const float*)d_in[5];
    const float* R1     = (const float*)d_in[6];
    const float* b1     = (const float*)d_in[7];
    const float* W2     = (const float*)d_in[8];
    const float* R2     = (const float*)d_in[9];
    const float* b2     = (const float*)d_in[10];
    const float* W3     = (const float*)d_in[11];
    const float* b3     = (const float*)d_in[12];
    const float* W4     = (const float*)d_in[13];
    const float* R4     = (const float*)d_in[14];
    const float* b4     = (const float*)d_in[15];

    const int N = in_sizes[0] / 128;
    const int E = in_sizes[1] / 2;
    const int* row = ei;
    const int* col = ei + E;

    // workspace layout (256B-aligned slabs) -- total ~210.5 MB
    size_t off = 0;
    auto alloc = [&](size_t bytes) -> void* {
        void* p = (char*)d_ws + off;
        off += (bytes + 255) & ~(size_t)255;
        return p;
    };
    int*   deg    = (int*)alloc((size_t)N * 4);
    int*   rp     = (int*)alloc((size_t)(N + 1) * 4);
    int*   cursor = (int*)alloc((size_t)N * 4);
    int*   colS   = (int*)alloc((size_t)E * 4);
    float* dinv   = (float*)alloc((size_t)N * 4);
    float* cinv   = (float*)alloc((size_t)N * 4);
    float* P      = (float*)alloc((size_t)N * 256 * 4);
    float* Q      = (float*)alloc((size_t)N * 256 * 4);
    (void)ws_size;

    // ---- CSR build (no memset/memcpy: kernels only) ----
    zero_int_kernel<<<(N + 255) / 256, 256, 0, stream>>>(deg, N);
    count_deg_kernel<<<(E + 255) / 256, 256, 0, stream>>>(row, deg, E);
    scan_kernel<<<1, 1024, 0, stream>>>(deg, rp, cursor, N);
    scales_kernel<<<(N + 255) / 256, 256, 0, stream>>>(deg, dinv, cinv, N);
    fill_csr_kernel<<<(E + 255) / 256, 256, 0, stream>>>(row, col, cursor, colS, E);

    dim3 aggGrid((N + 3) / 4);
    dim3 gemmGrid((N + 63) / 64);

    // ---- layer 0 (GCN): P = x + a0*(gcn_agg(x)@W0 + b0) ----
    agg_csr_kernel<128><<<aggGrid, 256, 0, stream>>>(x, 128, rp, colS, dinv, dinv, P, 128, N);
    gemm_ep_kernel<128, 2><<<gemmGrid, 256, 0, stream>>>(
        P, 128, 128, nullptr, 0, 0, W0, nullptr, b0, x, alpha, 0, P, N, 128);

    // ---- layer 1 (SAGE 128->256): Q = relu([mean(P)|P] @ [W1;R1] + b1) ----
    agg_csr_kernel<128><<<aggGrid, 256, 0, stream>>>(P, 128, rp, colS, nullptr, cinv, Q, 256, N);
    gemm_ep_kernel<256, 1><<<gemmGrid, 256, 0, stream>>>(
        Q, 128, 256, P, 128, 128, W1, R1, b1, nullptr, nullptr, 0, Q, N, 256);

    // ---- layer 2 (SAGE 256->256): P = relu([mean(Q)|Q] @ [W2;R2] + b2) ----
    agg_csr_kernel<256><<<aggGrid, 256, 0, stream>>>(Q, 256, rp, colS, nullptr, cinv, P, 256, N);
    gemm_ep_kernel<256, 1><<<gemmGrid, 256, 0, stream>>>(
        P, 256, 256, Q, 256, 256, W2, R2, b2, nullptr, nullptr, 0, P, N, 256);

    // ---- layer 3 (GCN): Q = P + a3*(gcn_agg(P)@W3 + b3) ----
    agg_csr_kernel<256><<<aggGrid, 256, 0, stream>>>(P, 256, rp, colS, dinv, dinv, Q, 256, N);
    gemm_ep_kernel<256, 2><<<gemmGrid, 256, 0, stream>>>(
        Q, 256, 256, nullptr, 0, 0, W3, nullptr, b3, P, alpha, 3, Q, N, 256);

    // ---- layer 4 (SAGE 256->112): out = [mean(Q)|Q] @ [W4;R4] + b4 ----
    agg_csr_kernel<256><<<aggGrid, 256, 0, stream>>>(Q, 256, rp, colS, nullptr, cinv, P, 256, N);
    gemm_ep_kernel<128, 0><<<gemmGrid, 256, 0, stream>>>(
        P, 256, 256, Q, 256, 256, W4, R4, b4, nullptr, nullptr, 0, (float*)d_out, N, 112);
}

// Round 3
// 1001.456 us; speedup vs baseline: 1.8853x; 1.8853x over previous
//
#include <hip/hip_runtime.h>

// ---------------------------------------------------------------------------
// SAGE_Re GNN forward, R3: bf16-MFMA GEMMs + bf16 feature storage.
// - CSR built per call (int atomics only)
// - agg: wave-per-node gather of bf16 rows (512B/256B), fp32 accumulate
// - GEMM: 128x128 tile, 4 waves, mfma_f32_16x16x32_bf16, fused epilogues
// - fp32 trunk preserved where it matters: L0 residual reads x (fp32);
//   only L3 residual reads a bf16 activation (one ~0.2% rounding).
// Workspace ~186 MB.
// ---------------------------------------------------------------------------

typedef __attribute__((ext_vector_type(8))) short bf16x8;
typedef __attribute__((ext_vector_type(4))) float f32x4;

__device__ __forceinline__ float bf2f(unsigned short u) {
    union { unsigned int i; float f; } v; v.i = ((unsigned int)u) << 16; return v.f;
}
__device__ __forceinline__ unsigned short f2bf(float f) {
    union { float f; unsigned int i; } v; v.f = f;
    unsigned int r = (v.i + 0x7fffu + ((v.i >> 16) & 1u)) >> 16;
    return (unsigned short)r;
}

// ---------------- CSR build ----------------

__global__ __launch_bounds__(256) void zero_int_kernel(int* __restrict__ p, int n)
{
    int i = blockIdx.x * 256 + threadIdx.x;
    if (i < n) p[i] = 0;
}

__global__ __launch_bounds__(256) void count_deg_kernel(
    const int* __restrict__ row, int* __restrict__ deg, int E)
{
    int e = blockIdx.x * 256 + threadIdx.x;
    if (e < E) atomicAdd(&deg[row[e]], 1);
}

__global__ __launch_bounds__(1024) void scan_kernel(
    const int* __restrict__ deg, int* __restrict__ rp,
    int* __restrict__ cursor, int n)
{
    __shared__ int wsum[16];
    int t = threadIdx.x;
    int lane = t & 63, w = t >> 6;
    if (t == 0) rp[0] = 0;
    int carry = 0;
    for (int base = 0; base < n; base += 1024) {
        int i = base + t;
        int xv = (i < n) ? deg[i] : 0;
        int s = xv;
        #pragma unroll
        for (int off = 1; off < 64; off <<= 1) {
            int v = __shfl_up(s, off, 64);
            if (lane >= off) s += v;
        }
        if (lane == 63) wsum[w] = s;
        __syncthreads();
        if (w == 0 && lane < 16) {
            int ws = wsum[lane];
            #pragma unroll
            for (int off = 1; off < 16; off <<= 1) {
                int v = __shfl_up(ws, off, 64);
                if (lane >= off) ws += v;
            }
            wsum[lane] = ws;
        }
        __syncthreads();
        int wo = (w == 0) ? 0 : wsum[w - 1];
        if (i < n) {
            int incl = carry + wo + s;
            rp[i + 1] = incl;
            cursor[i] = incl - xv;
        }
        carry += wsum[15];
        __syncthreads();
    }
}

__global__ __launch_bounds__(256) void scales_kernel(
    const int* __restrict__ deg, float* __restrict__ dinv,
    float* __restrict__ cinv, int n)
{
    int i = blockIdx.x * 256 + threadIdx.x;
    if (i >= n) return;
    int d = deg[i];
    float df = (float)d;
    dinv[i] = (d > 0) ? rsqrtf(df) : 0.0f;
    cinv[i] = 1.0f / fmaxf(df, 1.0f);
}

__global__ __launch_bounds__(256) void fill_csr_kernel(
    const int* __restrict__ row, const int* __restrict__ col,
    int* __restrict__ cursor, int* __restrict__ colS, int E)
{
    int e = blockIdx.x * 256 + threadIdx.x;
    if (e < E) {
        int p = atomicAdd(&cursor[row[e]], 1);
        colS[p] = col[e];
    }
}

// ---------------- prep: fp32 -> bf16 conversions ----------------

__global__ __launch_bounds__(256) void f32_to_bf16_kernel(
    const float* __restrict__ src, unsigned short* __restrict__ dst, int n4)
{
    int i = blockIdx.x * 256 + threadIdx.x;  // per float4
    if (i >= n4) return;
    float4 v = ((const float4*)src)[i];
    ushort4 o;
    o.x = f2bf(v.x); o.y = f2bf(v.y); o.z = f2bf(v.z); o.w = f2bf(v.w);
    ((ushort4*)dst)[i] = o;
}

// weights: dst[n][k] bf16 (ld = K1+K2) from row-major fp32 S1 [K1 x Nout], S2 [K2 x Nout]
__global__ __launch_bounds__(256) void prep_w_kernel(
    const float* __restrict__ S1, int K1,
    const float* __restrict__ S2, int K2,
    int Nout, unsigned short* __restrict__ dst)
{
    int Ktot = K1 + K2;
    int idx = blockIdx.x * 256 + threadIdx.x;
    if (idx >= Ktot * Nout) return;
    int n = idx / Ktot, k = idx - n * Ktot;
    float v = (k < K1) ? S1[(size_t)k * Nout + n] : S2[(size_t)(k - K1) * Nout + n];
    dst[idx] = f2bf(v);
}

// ---------------- aggregation: wave per node, bf16 rows ----------------
// out[i,:] = bf16( nscale[i] * sum_e escale[col] * bf2f(h[col,:]) )

template <int C>
__global__ __launch_bounds__(256) void agg_bf16_kernel(
    const unsigned short* __restrict__ h, int ldh,
    const int* __restrict__ rp, const int* __restrict__ cols,
    const float* __restrict__ escale, const float* __restrict__ nscale,
    unsigned short* __restrict__ out, int ldo, int n)
{
    constexpr int V = C / 64;  // bf16 per lane: 4 (C=256) or 2 (C=128)
    int node = blockIdx.x * 4 + (threadIdx.x >> 6);
    int lane = threadIdx.x & 63;
    if (node >= n) return;
    int s = rp[node], e = rp[node + 1];
    float acc[V];
    #pragma unroll
    for (int v = 0; v < V; ++v) acc[v] = 0.0f;
    int i = s;
    for (; i + 1 < e; i += 2) {
        int c0 = cols[i], c1 = cols[i + 1];
        float s0 = escale ? escale[c0] : 1.0f;
        float s1 = escale ? escale[c1] : 1.0f;
        if constexpr (V == 4) {
            ushort4 u0 = *(const ushort4*)(h + (size_t)c0 * ldh + lane * 4);
            ushort4 u1 = *(const ushort4*)(h + (size_t)c1 * ldh + lane * 4);
            acc[0] += s0 * bf2f(u0.x) + s1 * bf2f(u1.x);
            acc[1] += s0 * bf2f(u0.y) + s1 * bf2f(u1.y);
            acc[2] += s0 * bf2f(u0.z) + s1 * bf2f(u1.z);
            acc[3] += s0 * bf2f(u0.w) + s1 * bf2f(u1.w);
        } else {
            ushort2 u0 = *(const ushort2*)(h + (size_t)c0 * ldh + lane * 2);
            ushort2 u1 = *(const ushort2*)(h + (size_t)c1 * ldh + lane * 2);
            acc[0] += s0 * bf2f(u0.x) + s1 * bf2f(u1.x);
            acc[1] += s0 * bf2f(u0.y) + s1 * bf2f(u1.y);
        }
    }
    if (i < e) {
        int c0 = cols[i];
        float s0 = escale ? escale[c0] : 1.0f;
        if constexpr (V == 4) {
            ushort4 u0 = *(const ushort4*)(h + (size_t)c0 * ldh + lane * 4);
            acc[0] += s0 * bf2f(u0.x); acc[1] += s0 * bf2f(u0.y);
            acc[2] += s0 * bf2f(u0.z); acc[3] += s0 * bf2f(u0.w);
        } else {
            ushort2 u0 = *(const ushort2*)(h + (size_t)c0 * ldh + lane * 2);
            acc[0] += s0 * bf2f(u0.x); acc[1] += s0 * bf2f(u0.y);
        }
    }
    float ns = nscale[node];
    if constexpr (V == 4) {
        ushort4 o;
        o.x = f2bf(acc[0] * ns); o.y = f2bf(acc[1] * ns);
        o.z = f2bf(acc[2] * ns); o.w = f2bf(acc[3] * ns);
        *(ushort4*)(out + (size_t)node * ldo + lane * 4) = o;
    } else {
        ushort2 o;
        o.x = f2bf(acc[0] * ns); o.y = f2bf(acc[1] * ns);
        *(ushort2*)(out + (size_t)node * ldo + lane * 2) = o;
    }
}

// ---------------- bf16 MFMA GEMM, 128x128 tile ----------------
// out = epi([A1|A2] @ Bt^T + bias); A row-major bf16, Bt is [n][k] bf16.
// EPI 0: acc+bias   EPI 1: relu(acc+bias)   EPI 2: res + alpha*(acc+bias)
// 256 threads = 4 waves in 2x2; each wave: 64x64 via 4x4 mfma_f32_16x16x32_bf16.
// A-frag: lane holds A[m=lane&15][k=quad*8+j]; C/D: col=lane&15,row=quad*4+reg.

template <int EPI, bool RES_BF16, bool WF32, bool WB16>
__global__ __launch_bounds__(256) void mfma_gemm_kernel(
    const unsigned short* __restrict__ A1, int K1, int lda1,
    const unsigned short* __restrict__ A2, int K2, int lda2,
    const unsigned short* __restrict__ Bt,
    const float* __restrict__ bias,
    const void* __restrict__ res, int ldres,
    const float* __restrict__ alpha_ptr, int alpha_idx,
    float* __restrict__ outf, unsigned short* __restrict__ outb, int ldo,
    int M, int Nout)
{
    __shared__ unsigned short As[128][40];  // stride 40 shorts: b128 reads 2-way (free)
    __shared__ unsigned short Bs[128][40];
    int t = threadIdx.x;
    int m0 = blockIdx.x * 128, n0 = blockIdx.y * 128;
    int Ktot = K1 + K2;
    int w = t >> 6, lane = t & 63;
    int wm = w & 1, wn = w >> 1;          // wave at (wm,wn) of 2x2
    int q = lane >> 4, l16 = lane & 15;

    int sr = t >> 1;                       // staging row (A) / n-col (B): 0..127
    int sh = (t & 1) * 16;                 // staging k offset (shorts)

    f32x4 acc[4][4];
    #pragma unroll
    for (int i = 0; i < 4; ++i)
        #pragma unroll
        for (int j = 0; j < 4; ++j)
            #pragma unroll
            for (int r = 0; r < 4; ++r) acc[i][j][r] = 0.0f;

    for (int k0 = 0; k0 < Ktot; k0 += 32) {
        const unsigned short* Ap; int lda, kk;
        if (k0 < K1) { Ap = A1; lda = lda1; kk = k0; }
        else         { Ap = A2; lda = lda2; kk = k0 - K1; }
        // ---- stage A: 128 rows x 32 k, bf16, 32B per thread ----
        {
            int gm = m0 + sr;
            uint4 v0 = make_uint4(0, 0, 0, 0), v1 = v0;
            if (gm < M) {
                const unsigned short* ga = Ap + (size_t)gm * lda + kk + sh;
                v0 = *(const uint4*)ga;
                v1 = *(const uint4*)(ga + 8);
            }
            *(uint4*)&As[sr][sh] = v0;
            *(uint4*)&As[sr][sh + 8] = v1;
        }
        // ---- stage B: 128 n x 32 k from Bt[n][k] ----
        {
            int gn = n0 + sr;
            uint4 v0 = make_uint4(0, 0, 0, 0), v1 = v0;
            if (gn < Nout) {
                const unsigned short* gb = Bt + (size_t)gn * Ktot + k0 + sh;
                v0 = *(const uint4*)gb;
                v1 = *(const uint4*)(gb + 8);
            }
            *(uint4*)&Bs[sr][sh] = v0;
            *(uint4*)&Bs[sr][sh + 8] = v1;
        }
        __syncthreads();
        bf16x8 af[4], bfr[4];
        #pragma unroll
        for (int i = 0; i < 4; ++i)
            af[i] = *(const bf16x8*)&As[wm * 64 + i * 16 + l16][q * 8];
        #pragma unroll
        for (int j = 0; j < 4; ++j)
            bfr[j] = *(const bf16x8*)&Bs[wn * 64 + j * 16 + l16][q * 8];
        #pragma unroll
        for (int i = 0; i < 4; ++i)
            #pragma unroll
            for (int j = 0; j < 4; ++j)
                acc[i][j] = __builtin_amdgcn_mfma_f32_16x16x32_bf16(
                    af[i], bfr[j], acc[i][j], 0, 0, 0);
        __syncthreads();
    }

    float alpha = 0.0f;
    if (EPI == 2) alpha = alpha_ptr[alpha_idx];
    #pragma unroll
    for (int i = 0; i < 4; ++i) {
        #pragma unroll
        for (int j = 0; j < 4; ++j) {
            int n = n0 + wn * 64 + j * 16 + l16;
            if (n >= Nout) continue;
            float bv = bias[n];
            #pragma unroll
            for (int r = 0; r < 4; ++r) {
                int m = m0 + wm * 64 + i * 16 + q * 4 + r;
                if (m >= M) continue;
                float v = acc[i][j][r] + bv;
                if (EPI == 1) v = fmaxf(v, 0.0f);
                if (EPI == 2) {
                    float r0 = RES_BF16
                        ? bf2f(((const unsigned short*)res)[(size_t)m * ldres + n])
                        : ((const float*)res)[(size_t)m * ldres + n];
                    v = r0 + alpha * v;
                }
                if (WF32) outf[(size_t)m * ldo + n] = v;
                if (WB16) outb[(size_t)m * ldo + n] = f2bf(v);
            }
        }
    }
}

// ---------------------------------------------------------------------------

extern "C" void kernel_launch(void* const* d_in, const int* in_sizes, int n_in,
                              void* d_out, int out_size, void* d_ws, size_t ws_size,
                              hipStream_t stream)
{
    const float* x      = (const float*)d_in[0];
    const int*   ei     = (const int*)d_in[1];
    const float* alpha  = (const float*)d_in[2];
    const float* W0     = (const float*)d_in[3];
    const float* b0     = (const float*)d_in[4];
    const float* W1     = (const float*)d_in[5];
    const float* R1     = (const float*)d_in[6];
    const float* b1     = (const float*)d_in[7];
    const float* W2     = (const float*)d_in[8];
    const float* R2     = (const float*)d_in[9];
    const float* b2     = (const float*)d_in[10];
    const float* W3     = (const float*)d_in[11];
    const float* b3     = (const float*)d_in[12];
    const float* W4     = (const float*)d_in[13];
    const float* R4     = (const float*)d_in[14];
    const float* b4     = (const float*)d_in[15];

    const int N = in_sizes[0] / 128;
    const int E = in_sizes[1] / 2;
    const int* row = ei;
    const int* col = ei + E;

    size_t off = 0;
    auto alloc = [&](size_t bytes) -> void* {
        void* p = (char*)d_ws + off;
        off += (bytes + 255) & ~(size_t)255;
        return p;
    };
    int*   deg    = (int*)alloc((size_t)N * 4);
    int*   rp     = (int*)alloc((size_t)(N + 1) * 4);
    int*   cursor = (int*)alloc((size_t)N * 4);
    int*   colS   = (int*)alloc((size_t)E * 4);
    float* dinv   = (float*)alloc((size_t)N * 4);
    float* cinv   = (float*)alloc((size_t)N * 4);
    unsigned short* Wt0 = (unsigned short*)alloc((size_t)128 * 128 * 2);
    unsigned short* Wt1 = (unsigned short*)alloc((size_t)256 * 256 * 2);
    unsigned short* Wt2 = (unsigned short*)alloc((size_t)256 * 512 * 2);
    unsigned short* Wt3 = (unsigned short*)alloc((size_t)256 * 256 * 2);
    unsigned short* Wt4 = (unsigned short*)alloc((size_t)112 * 512 * 2);
    unsigned short* Xb  = (unsigned short*)alloc((size_t)N * 128 * 2);  // aliased as Hb (L0 out)
    unsigned short* Gb  = (unsigned short*)alloc((size_t)N * 256 * 2);
    unsigned short* Pb  = (unsigned short*)alloc((size_t)N * 256 * 2);
    unsigned short* Ab  = (unsigned short*)alloc((size_t)N * 256 * 2);
    unsigned short* Hb  = Xb;  // safe: Xb only read by L0 agg, Hb written by L0 gemm
    (void)ws_size;

    // ---- CSR build ----
    zero_int_kernel<<<(N + 255) / 256, 256, 0, stream>>>(deg, N);
    count_deg_kernel<<<(E + 255) / 256, 256, 0, stream>>>(row, deg, E);
    scan_kernel<<<1, 1024, 0, stream>>>(deg, rp, cursor, N);
    scales_kernel<<<(N + 255) / 256, 256, 0, stream>>>(deg, dinv, cinv, N);
    fill_csr_kernel<<<(E + 255) / 256, 256, 0, stream>>>(row, col, cursor, colS, E);

    // ---- prep: x -> bf16, weights -> bf16 [n][k] ----
    f32_to_bf16_kernel<<<(N * 32 + 255) / 256, 256, 0, stream>>>(x, Xb, N * 32);
    prep_w_kernel<<<(128 * 128 + 255) / 256, 256, 0, stream>>>(W0, 128, nullptr, 0, 128, Wt0);
    prep_w_kernel<<<(256 * 256 + 255) / 256, 256, 0, stream>>>(W1, 128, R1, 128, 256, Wt1);
    prep_w_kernel<<<(256 * 512 + 255) / 256, 256, 0, stream>>>(W2, 256, R2, 256, 256, Wt2);
    prep_w_kernel<<<(256 * 256 + 255) / 256, 256, 0, stream>>>(W3, 256, nullptr, 0, 256, Wt3);
    prep_w_kernel<<<(112 * 512 + 255) / 256, 256, 0, stream>>>(W4, 256, R4, 256, 112, Wt4);

    dim3 aggGrid((N + 3) / 4);
    dim3 g1((N + 127) / 128, 1), g2((N + 127) / 128, 2);

    // ---- L0 (GCN): Hb = bf16( x + a0*(gcn_agg(x)@W0 + b0) ) ----
    agg_bf16_kernel<128><<<aggGrid, 256, 0, stream>>>(Xb, 128, rp, colS, dinv, dinv, Ab, 128, N);
    mfma_gemm_kernel<2, false, false, true><<<g1, 256, 0, stream>>>(
        Ab, 128, 128, nullptr, 0, 0, Wt0, b0, x, 128, alpha, 0,
        nullptr, Hb, 128, N, 128);

    // ---- L1 (SAGE 128->256): Gb = relu([mean(Hb)|Hb]@[W1;R1]+b1) ----
    agg_bf16_kernel<128><<<aggGrid, 256, 0, stream>>>(Hb, 128, rp, colS, nullptr, cinv, Ab, 128, N);
    mfma_gemm_kernel<1, false, false, true><<<g2, 256, 0, stream>>>(
        Ab, 128, 128, Hb, 128, 128, Wt1, b1, nullptr, 0, nullptr, 0,
        nullptr, Gb, 256, N, 256);

    // ---- L2 (SAGE 256->256): Pb = relu([mean(Gb)|Gb]@[W2;R2]+b2) ----
    agg_bf16_kernel<256><<<aggGrid, 256, 0, stream>>>(Gb, 256, rp, colS, nullptr, cinv, Ab, 256, N);
    mfma_gemm_kernel<1, false, false, true><<<g2, 256, 0, stream>>>(
        Ab, 256, 256, Gb, 256, 256, Wt2, b2, nullptr, 0, nullptr, 0,
        nullptr, Pb, 256, N, 256);

    // ---- L3 (GCN): Gb = Pb + a3*(gcn_agg(Pb)@W3 + b3) ----
    agg_bf16_kernel<256><<<aggGrid, 256, 0, stream>>>(Pb, 256, rp, colS, dinv, dinv, Ab, 256, N);
    mfma_gemm_kernel<2, true, false, true><<<g2, 256, 0, stream>>>(
        Ab, 256, 256, nullptr, 0, 0, Wt3, b3, Pb, 256, alpha, 3,
        nullptr, Gb, 256, N, 256);

    // ---- L4 (SAGE 256->112): d_out = [mean(Gb)|Gb]@[W4;R4]+b4 (fp32) ----
    agg_bf16_kernel<256><<<aggGrid, 256, 0, stream>>>(Gb, 256, rp, colS, nullptr, cinv, Ab, 256, N);
    mfma_gemm_kernel<0, false, true, false><<<g1, 256, 0, stream>>>(
        Ab, 256, 256, Gb, 256, 256, Wt4, b4, nullptr, 0, nullptr, 0,
        (float*)d_out, nullptr, 112, N, 112);
}

// Round 4
// 883.674 us; speedup vs baseline: 2.1365x; 1.1333x over previous
//
#include <hip/hip_runtime.h>

// ---------------------------------------------------------------------------
// SAGE_Re GNN forward, R4.
// - agg: wave split across edges (2 or 4 edges concurrent) + unroll x2
//   -> 4 outstanding 16B gathers/wave; __shfl_xor cross-edge reduction.
// - GEMM: m97 recipe. BK=32, contiguous As[128][32] LDS, async
//   global_load_lds dwordx4 staging, ds_read_b128 frags, 16 MFMA/wave/chunk.
// - weights padded to n%128==0 so B staging needs no masks.
// ---------------------------------------------------------------------------

typedef __attribute__((ext_vector_type(8))) short bf16x8;
typedef __attribute__((ext_vector_type(4))) float f32x4;

__device__ __forceinline__ float bf2f(unsigned short u) {
    union { unsigned int i; float f; } v; v.i = ((unsigned int)u) << 16; return v.f;
}
__device__ __forceinline__ unsigned short f2bf(float f) {
    union { float f; unsigned int i; } v; v.f = f;
    unsigned int r = (v.i + 0x7fffu + ((v.i >> 16) & 1u)) >> 16;
    return (unsigned short)r;
}

// ---------------- CSR build ----------------

__global__ __launch_bounds__(256) void zero_int_kernel(int* __restrict__ p, int n)
{
    int i = blockIdx.x * 256 + threadIdx.x;
    if (i < n) p[i] = 0;
}

__global__ __launch_bounds__(256) void count_deg_kernel(
    const int* __restrict__ row, int* __restrict__ deg, int E)
{
    int e = blockIdx.x * 256 + threadIdx.x;
    if (e < E) atomicAdd(&deg[row[e]], 1);
}

__global__ __launch_bounds__(1024) void scan_kernel(
    const int* __restrict__ deg, int* __restrict__ rp,
    int* __restrict__ cursor, int n)
{
    __shared__ int wsum[16];
    int t = threadIdx.x;
    int lane = t & 63, w = t >> 6;
    if (t == 0) rp[0] = 0;
    int carry = 0;
    for (int base = 0; base < n; base += 1024) {
        int i = base + t;
        int xv = (i < n) ? deg[i] : 0;
        int s = xv;
        #pragma unroll
        for (int off = 1; off < 64; off <<= 1) {
            int v = __shfl_up(s, off, 64);
            if (lane >= off) s += v;
        }
        if (lane == 63) wsum[w] = s;
        __syncthreads();
        if (w == 0 && lane < 16) {
            int ws = wsum[lane];
            #pragma unroll
            for (int off = 1; off < 16; off <<= 1) {
                int v = __shfl_up(ws, off, 64);
                if (lane >= off) ws += v;
            }
            wsum[lane] = ws;
        }
        __syncthreads();
        int wo = (w == 0) ? 0 : wsum[w - 1];
        if (i < n) {
            int incl = carry + wo + s;
            rp[i + 1] = incl;
            cursor[i] = incl - xv;
        }
        carry += wsum[15];
        __syncthreads();
    }
}

__global__ __launch_bounds__(256) void scales_kernel(
    const int* __restrict__ deg, float* __restrict__ dinv,
    float* __restrict__ cinv, int n)
{
    int i = blockIdx.x * 256 + threadIdx.x;
    if (i >= n) return;
    int d = deg[i];
    float df = (float)d;
    dinv[i] = (d > 0) ? rsqrtf(df) : 0.0f;
    cinv[i] = 1.0f / fmaxf(df, 1.0f);
}

__global__ __launch_bounds__(256) void fill_csr_kernel(
    const int* __restrict__ row, const int* __restrict__ col,
    int* __restrict__ cursor, int* __restrict__ colS, int E)
{
    int e = blockIdx.x * 256 + threadIdx.x;
    if (e < E) {
        int p = atomicAdd(&cursor[row[e]], 1);
        colS[p] = col[e];
    }
}

// ---------------- prep ----------------

__global__ __launch_bounds__(256) void f32_to_bf16_kernel(
    const float* __restrict__ src, unsigned short* __restrict__ dst, int n4)
{
    int i = blockIdx.x * 256 + threadIdx.x;
    if (i >= n4) return;
    float4 v = ((const float4*)src)[i];
    ushort4 o;
    o.x = f2bf(v.x); o.y = f2bf(v.y); o.z = f2bf(v.z); o.w = f2bf(v.w);
    ((ushort4*)dst)[i] = o;
}

// dst[n][k] bf16 for n<Npad (zeros for n>=Nout); sources row-major fp32.
__global__ __launch_bounds__(256) void prep_w_kernel(
    const float* __restrict__ S1, int K1,
    const float* __restrict__ S2, int K2,
    int Nout, int Npad, unsigned short* __restrict__ dst)
{
    int Ktot = K1 + K2;
    int idx = blockIdx.x * 256 + threadIdx.x;
    if (idx >= Npad * Ktot) return;
    int n = idx / Ktot, k = idx - n * Ktot;
    float v = 0.0f;
    if (n < Nout)
        v = (k < K1) ? S1[(size_t)k * Nout + n] : S2[(size_t)(k - K1) * Nout + n];
    dst[idx] = f2bf(v);
}

// ---------------- aggregation: wave per node, multi-edge lanes ----------------
// out[i,:] = bf16( nscale[i] * sum_e escale[col] * bf2f(h[col,:]) )

__device__ __forceinline__ void acc8(float* acc, uint4 u, float s) {
    unsigned int xs[4] = {u.x, u.y, u.z, u.w};
    #pragma unroll
    for (int p = 0; p < 4; ++p) {
        union { unsigned int i; float f; } lo, hi;
        lo.i = xs[p] << 16;
        hi.i = xs[p] & 0xffff0000u;
        acc[2 * p]     += s * lo.f;
        acc[2 * p + 1] += s * hi.f;
    }
}

template <int C, bool HAS_ES>
__global__ __launch_bounds__(256) void agg_bf16_kernel(
    const unsigned short* __restrict__ h, int ldh,
    const int* __restrict__ rp, const int* __restrict__ cols,
    const float* __restrict__ escale, const float* __restrict__ nscale,
    unsigned short* __restrict__ out, int ldo, int n)
{
    constexpr int LPE = (C == 256) ? 32 : 16;  // lanes per edge
    constexpr int EPG = 64 / LPE;              // edges per group (2 or 4)
    int node = blockIdx.x * 4 + (threadIdx.x >> 6);
    if (node >= n) return;
    int lane = threadIdx.x & 63;
    int grp = lane / LPE, sub = lane % LPE;
    const unsigned short* hc = h + sub * 8;    // this lane's 8-channel slice

    int s = rp[node], e = rp[node + 1];
    float acc[8];
    #pragma unroll
    for (int k = 0; k < 8; ++k) acc[k] = 0.0f;

    for (int i = s; i < e; i += 2 * EPG) {
        int i0 = i + grp, i1 = i + EPG + grp;
        int c0 = (i0 < e) ? cols[i0] : 0;
        int c1 = (i1 < e) ? cols[i1] : 0;
        float s0 = (i0 < e) ? (HAS_ES ? escale[c0] : 1.0f) : 0.0f;
        float s1 = (i1 < e) ? (HAS_ES ? escale[c1] : 1.0f) : 0.0f;
        uint4 u0 = *(const uint4*)(hc + (size_t)c0 * ldh);
        uint4 u1 = *(const uint4*)(hc + (size_t)c1 * ldh);
        acc8(acc, u0, s0);
        acc8(acc, u1, s1);
    }

    // reduce across edge groups (lane bits >= log2(LPE))
    #pragma unroll
    for (int k = 0; k < 8; ++k) {
        if (EPG == 4) acc[k] += __shfl_xor(acc[k], 16, 64);
        acc[k] += __shfl_xor(acc[k], 32, 64);
    }

    if (grp == 0) {
        float ns = nscale[node];
        uint4 o;
        unsigned int* op = (unsigned int*)&o;
        #pragma unroll
        for (int p = 0; p < 4; ++p) {
            unsigned short a = f2bf(acc[2 * p] * ns);
            unsigned short b = f2bf(acc[2 * p + 1] * ns);
            op[p] = (unsigned int)a | ((unsigned int)b << 16);
        }
        *(uint4*)(out + (size_t)node * ldo + sub * 8) = o;
    }
}

// ---------------- bf16 MFMA GEMM, 128x128 tile, async LDS staging -----------
// out = epi([A1|A2] @ Bt^T + bias); A row-major bf16; Bt [Npad][Ktot] bf16.
// 256 thr = 4 waves 2x2, each 64x64 via 4x4 mfma_f32_16x16x32_bf16, BK=32.

__device__ __forceinline__ void g2l16(const unsigned short* g, unsigned short* l) {
    __builtin_amdgcn_global_load_lds(
        (const __attribute__((address_space(1))) unsigned int*)g,
        (__attribute__((address_space(3))) unsigned int*)l, 16, 0, 0);
}

template <int EPI, bool RES_BF16, bool WF32, bool WB16>
__global__ __launch_bounds__(256) void mfma_gemm_kernel(
    const unsigned short* __restrict__ A1, int K1, int lda1,
    const unsigned short* __restrict__ A2, int K2, int lda2,
    const unsigned short* __restrict__ Bt,
    const float* __restrict__ bias,
    const void* __restrict__ res, int ldres,
    const float* __restrict__ alpha_ptr, int alpha_idx,
    float* __restrict__ outf, unsigned short* __restrict__ outb, int ldo,
    int M, int Nout)
{
    __shared__ unsigned short As[128 * 32];   // row-major [128][32], contiguous
    __shared__ unsigned short Bs[128 * 32];
    int t = threadIdx.x;
    int m0 = blockIdx.x * 128, n0 = blockIdx.y * 128;
    int Ktot = K1 + K2;
    int w = t >> 6, lane = t & 63;
    int wm = w & 1, wn = w >> 1;
    int q = lane >> 4, l16 = lane & 15;

    int roff = t >> 2;            // 0..63 (row within half-tile)
    int koff = (t & 3) * 8;       // k offset in shorts

    // clamped A-row addresses (stores are masked later; clamped loads stay in-bounds)
    int gmA0 = m0 + roff;       if (gmA0 >= M) gmA0 = M - 1;
    int gmA1 = m0 + 64 + roff;  if (gmA1 >= M) gmA1 = M - 1;
    int gnB0 = n0 + roff;
    int gnB1 = n0 + 64 + roff;

    // wave-uniform LDS bases for the 4 staging instructions
    unsigned short* ldsA0 = As + w * 512;            // bytes: w*1024
    unsigned short* ldsA1 = As + 2048 + w * 512;     // + 4096B
    unsigned short* ldsB0 = Bs + w * 512;
    unsigned short* ldsB1 = Bs + 2048 + w * 512;

    f32x4 acc[4][4];
    #pragma unroll
    for (int i = 0; i < 4; ++i)
        #pragma unroll
        for (int j = 0; j < 4; ++j)
            #pragma unroll
            for (int r = 0; r < 4; ++r) acc[i][j][r] = 0.0f;

    for (int k0 = 0; k0 < Ktot; k0 += 32) {
        const unsigned short* Ap; int lda, kk;
        if (k0 < K1) { Ap = A1; lda = lda1; kk = k0; }
        else         { Ap = A2; lda = lda2; kk = k0 - K1; }
        g2l16(Ap + (size_t)gmA0 * lda + kk + koff, ldsA0);
        g2l16(Ap + (size_t)gmA1 * lda + kk + koff, ldsA1);
        g2l16(Bt + (size_t)gnB0 * Ktot + k0 + koff, ldsB0);
        g2l16(Bt + (size_t)gnB1 * Ktot + k0 + koff, ldsB1);
        __syncthreads();
        bf16x8 af[4], bfr[4];
        #pragma unroll
        for (int i = 0; i < 4; ++i)
            af[i] = *(const bf16x8*)&As[(wm * 64 + i * 16 + l16) * 32 + q * 8];
        #pragma unroll
        for (int j = 0; j < 4; ++j)
            bfr[j] = *(const bf16x8*)&Bs[(wn * 64 + j * 16 + l16) * 32 + q * 8];
        #pragma unroll
        for (int i = 0; i < 4; ++i)
            #pragma unroll
            for (int j = 0; j < 4; ++j)
                acc[i][j] = __builtin_amdgcn_mfma_f32_16x16x32_bf16(
                    af[i], bfr[j], acc[i][j], 0, 0, 0);
        __syncthreads();
    }

    float alpha = 0.0f;
    if (EPI == 2) alpha = alpha_ptr[alpha_idx];
    #pragma unroll
    for (int i = 0; i < 4; ++i) {
        #pragma unroll
        for (int j = 0; j < 4; ++j) {
            int n = n0 + wn * 64 + j * 16 + l16;
            if (n >= Nout) continue;
            float bv = bias[n];
            #pragma unroll
            for (int r = 0; r < 4; ++r) {
                int m = m0 + wm * 64 + i * 16 + q * 4 + r;
                if (m >= M) continue;
                float v = acc[i][j][r] + bv;
                if (EPI == 1) v = fmaxf(v, 0.0f);
                if (EPI == 2) {
                    float r0 = RES_BF16
                        ? bf2f(((const unsigned short*)res)[(size_t)m * ldres + n])
                        : ((const float*)res)[(size_t)m * ldres + n];
                    v = r0 + alpha * v;
                }
                if (WF32) outf[(size_t)m * ldo + n] = v;
                if (WB16) outb[(size_t)m * ldo + n] = f2bf(v);
            }
        }
    }
}

// ---------------------------------------------------------------------------

extern "C" void kernel_launch(void* const* d_in, const int* in_sizes, int n_in,
                              void* d_out, int out_size, void* d_ws, size_t ws_size,
                              hipStream_t stream)
{
    const float* x      = (const float*)d_in[0];
    const int*   ei     = (const int*)d_in[1];
    const float* alpha  = (const float*)d_in[2];
    const float* W0     = (const float*)d_in[3];
    const float* b0     = (const float*)d_in[4];
    const float* W1     = (const float*)d_in[5];
    const float* R1     = (const float*)d_in[6];
    const float* b1     = (const float*)d_in[7];
    const float* W2     = (const float*)d_in[8];
    const float* R2     = (const float*)d_in[9];
    const float* b2     = (const float*)d_in[10];
    const float* W3     = (const float*)d_in[11];
    const float* b3     = (const float*)d_in[12];
    const float* W4     = (const float*)d_in[13];
    const float* R4     = (const float*)d_in[14];
    const float* b4     = (const float*)d_in[15];

    const int N = in_sizes[0] / 128;
    const int E = in_sizes[1] / 2;
    const int* row = ei;
    const int* col = ei + E;

    size_t off = 0;
    auto alloc = [&](size_t bytes) -> void* {
        void* p = (char*)d_ws + off;
        off += (bytes + 255) & ~(size_t)255;
        return p;
    };
    int*   deg    = (int*)alloc((size_t)N * 4);
    int*   rp     = (int*)alloc((size_t)(N + 1) * 4);
    int*   cursor = (int*)alloc((size_t)N * 4);
    int*   colS   = (int*)alloc((size_t)E * 4);
    float* dinv   = (float*)alloc((size_t)N * 4);
    float* cinv   = (float*)alloc((size_t)N * 4);
    unsigned short* Wt0 = (unsigned short*)alloc((size_t)128 * 128 * 2);
    unsigned short* Wt1 = (unsigned short*)alloc((size_t)256 * 256 * 2);
    unsigned short* Wt2 = (unsigned short*)alloc((size_t)256 * 512 * 2);
    unsigned short* Wt3 = (unsigned short*)alloc((size_t)256 * 256 * 2);
    unsigned short* Wt4 = (unsigned short*)alloc((size_t)128 * 512 * 2);  // padded 112->128
    unsigned short* Xb  = (unsigned short*)alloc((size_t)N * 128 * 2);
    unsigned short* Gb  = (unsigned short*)alloc((size_t)N * 256 * 2);
    unsigned short* Pb  = (unsigned short*)alloc((size_t)N * 256 * 2);
    unsigned short* Ab  = (unsigned short*)alloc((size_t)N * 256 * 2);
    unsigned short* Hb  = Xb;  // alias: Xb only read by L0 agg before Hb written
    (void)ws_size;

    // ---- CSR build ----
    zero_int_kernel<<<(N + 255) / 256, 256, 0, stream>>>(deg, N);
    count_deg_kernel<<<(E + 255) / 256, 256, 0, stream>>>(row, deg, E);
    scan_kernel<<<1, 1024, 0, stream>>>(deg, rp, cursor, N);
    scales_kernel<<<(N + 255) / 256, 256, 0, stream>>>(deg, dinv, cinv, N);
    fill_csr_kernel<<<(E + 255) / 256, 256, 0, stream>>>(row, col, cursor, colS, E);

    // ---- prep ----
    f32_to_bf16_kernel<<<(N * 32 + 255) / 256, 256, 0, stream>>>(x, Xb, N * 32);
    prep_w_kernel<<<(128 * 128 + 255) / 256, 256, 0, stream>>>(W0, 128, nullptr, 0, 128, 128, Wt0);
    prep_w_kernel<<<(256 * 256 + 255) / 256, 256, 0, stream>>>(W1, 128, R1, 128, 256, 256, Wt1);
    prep_w_kernel<<<(256 * 512 + 255) / 256, 256, 0, stream>>>(W2, 256, R2, 256, 256, 256, Wt2);
    prep_w_kernel<<<(256 * 256 + 255) / 256, 256, 0, stream>>>(W3, 256, nullptr, 0, 256, 256, Wt3);
    prep_w_kernel<<<(128 * 512 + 255) / 256, 256, 0, stream>>>(W4, 256, R4, 256, 112, 128, Wt4);

    dim3 aggGrid((N + 3) / 4);
    dim3 g1((N + 127) / 128, 1), g2((N + 127) / 128, 2);

    // ---- L0 (GCN): Hb = bf16( x + a0*(gcn_agg(x)@W0 + b0) ) ----
    agg_bf16_kernel<128, true><<<aggGrid, 256, 0, stream>>>(Xb, 128, rp, colS, dinv, dinv, Ab, 128, N);
    mfma_gemm_kernel<2, false, false, true><<<g1, 256, 0, stream>>>(
        Ab, 128, 128, nullptr, 0, 0, Wt0, b0, x, 128, alpha, 0,
        nullptr, Hb, 128, N, 128);

    // ---- L1 (SAGE 128->256): Gb = relu([mean(Hb)|Hb]@[W1;R1]+b1) ----
    agg_bf16_kernel<128, false><<<aggGrid, 256, 0, stream>>>(Hb, 128, rp, colS, nullptr, cinv, Ab, 128, N);
    mfma_gemm_kernel<1, false, false, true><<<g2, 256, 0, stream>>>(
        Ab, 128, 128, Hb, 128, 128, Wt1, b1, nullptr, 0, nullptr, 0,
        nullptr, Gb, 256, N, 256);

    // ---- L2 (SAGE 256->256): Pb = relu([mean(Gb)|Gb]@[W2;R2]+b2) ----
    agg_bf16_kernel<256, false><<<aggGrid, 256, 0, stream>>>(Gb, 256, rp, colS, nullptr, cinv, Ab, 256, N);
    mfma_gemm_kernel<1, false, false, true><<<g2, 256, 0, stream>>>(
        Ab, 256, 256, Gb, 256, 256, Wt2, b2, nullptr, 0, nullptr, 0,
        nullptr, Pb, 256, N, 256);

    // ---- L3 (GCN): Gb = Pb + a3*(gcn_agg(Pb)@W3 + b3) ----
    agg_bf16_kernel<256, true><<<aggGrid, 256, 0, stream>>>(Pb, 256, rp, colS, dinv, dinv, Ab, 256, N);
    mfma_gemm_kernel<2, true, false, true><<<g2, 256, 0, stream>>>(
        Ab, 256, 256, nullptr, 0, 0, Wt3, b3, Pb, 256, alpha, 3,
        nullptr, Gb, 256, N, 256);

    // ---- L4 (SAGE 256->112): d_out = [mean(Gb)|Gb]@[W4;R4]+b4 (fp32) ----
    agg_bf16_kernel<256, false><<<aggGrid, 256, 0, stream>>>(Gb, 256, rp, colS, nullptr, cinv, Ab, 256, N);
    mfma_gemm_kernel<0, false, true, false><<<g1, 256, 0, stream>>>(
        Ab, 256, 256, Gb, 256, 256, Wt4, b4, nullptr, 0, nullptr, 0,
        (float*)d_out, nullptr, 112, N, 112);
}

// Round 5
// 781.662 us; speedup vs baseline: 2.4154x; 1.1305x over previous
//
#include <hip/hip_runtime.h>

// ---------------------------------------------------------------------------
// SAGE_Re GNN forward, R5.
// - CSR scan: 3-phase multi-block (was single-block, 95 us serial hotspot);
//   scales (dinv/cinv) folded into phase 3.
// - agg C=256: 4 gathers in flight per lane (was 2).
// - GEMM: m97 recipe unchanged (BK=32, global_load_lds dwordx4, 16 MFMA/wave).
// ---------------------------------------------------------------------------

typedef __attribute__((ext_vector_type(8))) short bf16x8;
typedef __attribute__((ext_vector_type(4))) float f32x4;

__device__ __forceinline__ float bf2f(unsigned short u) {
    union { unsigned int i; float f; } v; v.i = ((unsigned int)u) << 16; return v.f;
}
__device__ __forceinline__ unsigned short f2bf(float f) {
    union { float f; unsigned int i; } v; v.f = f;
    unsigned int r = (v.i + 0x7fffu + ((v.i >> 16) & 1u)) >> 16;
    return (unsigned short)r;
}

// ---------------- CSR build ----------------

__global__ __launch_bounds__(256) void zero_int_kernel(int* __restrict__ p, int n)
{
    int i = blockIdx.x * 256 + threadIdx.x;
    if (i < n) p[i] = 0;
}

__global__ __launch_bounds__(256) void count_deg_kernel(
    const int* __restrict__ row, int* __restrict__ deg, int E)
{
    int e = blockIdx.x * 256 + threadIdx.x;
    if (e < E) atomicAdd(&deg[row[e]], 1);
}

// phase 1: each block scans 2048 elements locally; rp[i+1] = local inclusive
__global__ __launch_bounds__(1024) void scan_p1_kernel(
    const int* __restrict__ deg, int* __restrict__ rp,
    int* __restrict__ bsum, int n)
{
    __shared__ int wsum[16];
    int t = threadIdx.x, lane = t & 63, w = t >> 6;
    int base = blockIdx.x * 2048;
    int carry = 0;
    #pragma unroll
    for (int half = 0; half < 2; ++half) {
        int i = base + half * 1024 + t;
        int xv = (i < n) ? deg[i] : 0;
        int s = xv;
        #pragma unroll
        for (int off = 1; off < 64; off <<= 1) {
            int v = __shfl_up(s, off, 64);
            if (lane >= off) s += v;
        }
        if (lane == 63) wsum[w] = s;
        __syncthreads();
        if (w == 0 && lane < 16) {
            int ws = wsum[lane];
            #pragma unroll
            for (int off = 1; off < 16; off <<= 1) {
                int v = __shfl_up(ws, off, 64);
                if (lane >= off) ws += v;
            }
            wsum[lane] = ws;
        }
        __syncthreads();
        int wo = (w == 0) ? 0 : wsum[w - 1];
        if (i < n) rp[i + 1] = carry + wo + s;
        carry += wsum[15];
        if (half == 0) __syncthreads();
    }
    if (t == 0) bsum[blockIdx.x] = carry;
}

// phase 2: one wave exclusive-scans the block sums (B <= 64)
__global__ __launch_bounds__(64) void scan_p2_kernel(int* __restrict__ bsum, int B)
{
    int lane = threadIdx.x;
    int v = (lane < B) ? bsum[lane] : 0;
    int s = v;
    #pragma unroll
    for (int off = 1; off < 64; off <<= 1) {
        int u = __shfl_up(s, off, 64);
        if (lane >= off) s += u;
    }
    if (lane < B) bsum[lane] = s - v;
}

// phase 3: add block offsets; emit cursor, dinv, cinv; set rp[0]
__global__ __launch_bounds__(1024) void scan_p3_kernel(
    const int* __restrict__ deg, int* __restrict__ rp,
    int* __restrict__ cursor, const int* __restrict__ bsum,
    float* __restrict__ dinv, float* __restrict__ cinv, int n)
{
    int boff = bsum[blockIdx.x];
    int base = blockIdx.x * 2048;
    #pragma unroll
    for (int half = 0; half < 2; ++half) {
        int i = base + half * 1024 + threadIdx.x;
        if (i < n) {
            int d = deg[i];
            int incl = rp[i + 1] + boff;
            rp[i + 1] = incl;
            cursor[i] = incl - d;
            float df = (float)d;
            dinv[i] = (d > 0) ? rsqrtf(df) : 0.0f;
            cinv[i] = 1.0f / fmaxf(df, 1.0f);
        }
    }
    if (blockIdx.x == 0 && threadIdx.x == 0) rp[0] = 0;
}

__global__ __launch_bounds__(256) void fill_csr_kernel(
    const int* __restrict__ row, const int* __restrict__ col,
    int* __restrict__ cursor, int* __restrict__ colS, int E)
{
    int e = blockIdx.x * 256 + threadIdx.x;
    if (e < E) {
        int p = atomicAdd(&cursor[row[e]], 1);
        colS[p] = col[e];
    }
}

// ---------------- prep ----------------

__global__ __launch_bounds__(256) void f32_to_bf16_kernel(
    const float* __restrict__ src, unsigned short* __restrict__ dst, int n4)
{
    int i = blockIdx.x * 256 + threadIdx.x;
    if (i >= n4) return;
    float4 v = ((const float4*)src)[i];
    ushort4 o;
    o.x = f2bf(v.x); o.y = f2bf(v.y); o.z = f2bf(v.z); o.w = f2bf(v.w);
    ((ushort4*)dst)[i] = o;
}

// dst[n][k] bf16 for n<Npad (zeros for n>=Nout); sources row-major fp32.
__global__ __launch_bounds__(256) void prep_w_kernel(
    const float* __restrict__ S1, int K1,
    const float* __restrict__ S2, int K2,
    int Nout, int Npad, unsigned short* __restrict__ dst)
{
    int Ktot = K1 + K2;
    int idx = blockIdx.x * 256 + threadIdx.x;
    if (idx >= Npad * Ktot) return;
    int n = idx / Ktot, k = idx - n * Ktot;
    float v = 0.0f;
    if (n < Nout)
        v = (k < K1) ? S1[(size_t)k * Nout + n] : S2[(size_t)(k - K1) * Nout + n];
    dst[idx] = f2bf(v);
}

// ---------------- aggregation: wave per node, multi-edge lanes ----------------
// out[i,:] = bf16( nscale[i] * sum_e escale[col] * bf2f(h[col,:]) )

__device__ __forceinline__ void acc8(float* acc, uint4 u, float s) {
    unsigned int xs[4] = {u.x, u.y, u.z, u.w};
    #pragma unroll
    for (int p = 0; p < 4; ++p) {
        union { unsigned int i; float f; } lo, hi;
        lo.i = xs[p] << 16;
        hi.i = xs[p] & 0xffff0000u;
        acc[2 * p]     += s * lo.f;
        acc[2 * p + 1] += s * hi.f;
    }
}

template <int C, bool HAS_ES>
__global__ __launch_bounds__(256) void agg_bf16_kernel(
    const unsigned short* __restrict__ h, int ldh,
    const int* __restrict__ rp, const int* __restrict__ cols,
    const float* __restrict__ escale, const float* __restrict__ nscale,
    unsigned short* __restrict__ out, int ldo, int n)
{
    constexpr int LPE = (C == 256) ? 32 : 16;  // lanes per edge
    constexpr int EPG = 64 / LPE;              // edges per group (2 or 4)
    constexpr int UNR = (C == 256) ? 4 : 2;    // gathers in flight per lane
    int node = blockIdx.x * 4 + (threadIdx.x >> 6);
    if (node >= n) return;
    int lane = threadIdx.x & 63;
    int grp = lane / LPE, sub = lane % LPE;
    const unsigned short* hc = h + sub * 8;

    int s = rp[node], e = rp[node + 1];
    float acc[8];
    #pragma unroll
    for (int k = 0; k < 8; ++k) acc[k] = 0.0f;

    for (int i = s; i < e; i += UNR * EPG) {
        int cc[UNR]; float sc[UNR]; uint4 uu[UNR];
        #pragma unroll
        for (int u = 0; u < UNR; ++u) {
            int ii = i + u * EPG + grp;
            bool valid = ii < e;
            int c = valid ? cols[ii] : 0;
            cc[u] = c;
            sc[u] = valid ? (HAS_ES ? escale[c] : 1.0f) : 0.0f;
        }
        #pragma unroll
        for (int u = 0; u < UNR; ++u)
            uu[u] = *(const uint4*)(hc + (size_t)cc[u] * ldh);
        #pragma unroll
        for (int u = 0; u < UNR; ++u)
            acc8(acc, uu[u], sc[u]);
    }

    #pragma unroll
    for (int k = 0; k < 8; ++k) {
        if (EPG == 4) acc[k] += __shfl_xor(acc[k], 16, 64);
        acc[k] += __shfl_xor(acc[k], 32, 64);
    }

    if (grp == 0) {
        float ns = nscale[node];
        uint4 o;
        unsigned int* op = (unsigned int*)&o;
        #pragma unroll
        for (int p = 0; p < 4; ++p) {
            unsigned short a = f2bf(acc[2 * p] * ns);
            unsigned short b = f2bf(acc[2 * p + 1] * ns);
            op[p] = (unsigned int)a | ((unsigned int)b << 16);
        }
        *(uint4*)(out + (size_t)node * ldo + sub * 8) = o;
    }
}

// ---------------- bf16 MFMA GEMM, 128x128 tile, async LDS staging -----------

__device__ __forceinline__ void g2l16(const unsigned short* g, unsigned short* l) {
    __builtin_amdgcn_global_load_lds(
        (const __attribute__((address_space(1))) unsigned int*)g,
        (__attribute__((address_space(3))) unsigned int*)l, 16, 0, 0);
}

template <int EPI, bool RES_BF16, bool WF32, bool WB16>
__global__ __launch_bounds__(256) void mfma_gemm_kernel(
    const unsigned short* __restrict__ A1, int K1, int lda1,
    const unsigned short* __restrict__ A2, int K2, int lda2,
    const unsigned short* __restrict__ Bt,
    const float* __restrict__ bias,
    const void* __restrict__ res, int ldres,
    const float* __restrict__ alpha_ptr, int alpha_idx,
    float* __restrict__ outf, unsigned short* __restrict__ outb, int ldo,
    int M, int Nout)
{
    __shared__ unsigned short As[128 * 32];
    __shared__ unsigned short Bs[128 * 32];
    int t = threadIdx.x;
    int m0 = blockIdx.x * 128, n0 = blockIdx.y * 128;
    int Ktot = K1 + K2;
    int w = t >> 6, lane = t & 63;
    int wm = w & 1, wn = w >> 1;
    int q = lane >> 4, l16 = lane & 15;

    int roff = t >> 2;
    int koff = (t & 3) * 8;

    int gmA0 = m0 + roff;       if (gmA0 >= M) gmA0 = M - 1;
    int gmA1 = m0 + 64 + roff;  if (gmA1 >= M) gmA1 = M - 1;
    int gnB0 = n0 + roff;
    int gnB1 = n0 + 64 + roff;

    unsigned short* ldsA0 = As + w * 512;
    unsigned short* ldsA1 = As + 2048 + w * 512;
    unsigned short* ldsB0 = Bs + w * 512;
    unsigned short* ldsB1 = Bs + 2048 + w * 512;

    f32x4 acc[4][4];
    #pragma unroll
    for (int i = 0; i < 4; ++i)
        #pragma unroll
        for (int j = 0; j < 4; ++j)
            #pragma unroll
            for (int r = 0; r < 4; ++r) acc[i][j][r] = 0.0f;

    for (int k0 = 0; k0 < Ktot; k0 += 32) {
        const unsigned short* Ap; int lda, kk;
        if (k0 < K1) { Ap = A1; lda = lda1; kk = k0; }
        else         { Ap = A2; lda = lda2; kk = k0 - K1; }
        g2l16(Ap + (size_t)gmA0 * lda + kk + koff, ldsA0);
        g2l16(Ap + (size_t)gmA1 * lda + kk + koff, ldsA1);
        g2l16(Bt + (size_t)gnB0 * Ktot + k0 + koff, ldsB0);
        g2l16(Bt + (size_t)gnB1 * Ktot + k0 + koff, ldsB1);
        __syncthreads();
        bf16x8 af[4], bfr[4];
        #pragma unroll
        for (int i = 0; i < 4; ++i)
            af[i] = *(const bf16x8*)&As[(wm * 64 + i * 16 + l16) * 32 + q * 8];
        #pragma unroll
        for (int j = 0; j < 4; ++j)
            bfr[j] = *(const bf16x8*)&Bs[(wn * 64 + j * 16 + l16) * 32 + q * 8];
        #pragma unroll
        for (int i = 0; i < 4; ++i)
            #pragma unroll
            for (int j = 0; j < 4; ++j)
                acc[i][j] = __builtin_amdgcn_mfma_f32_16x16x32_bf16(
                    af[i], bfr[j], acc[i][j], 0, 0, 0);
        __syncthreads();
    }

    float alpha = 0.0f;
    if (EPI == 2) alpha = alpha_ptr[alpha_idx];
    #pragma unroll
    for (int i = 0; i < 4; ++i) {
        #pragma unroll
        for (int j = 0; j < 4; ++j) {
            int n = n0 + wn * 64 + j * 16 + l16;
            if (n >= Nout) continue;
            float bv = bias[n];
            #pragma unroll
            for (int r = 0; r < 4; ++r) {
                int m = m0 + wm * 64 + i * 16 + q * 4 + r;
                if (m >= M) continue;
                float v = acc[i][j][r] + bv;
                if (EPI == 1) v = fmaxf(v, 0.0f);
                if (EPI == 2) {
                    float r0 = RES_BF16
                        ? bf2f(((const unsigned short*)res)[(size_t)m * ldres + n])
                        : ((const float*)res)[(size_t)m * ldres + n];
                    v = r0 + alpha * v;
                }
                if (WF32) outf[(size_t)m * ldo + n] = v;
                if (WB16) outb[(size_t)m * ldo + n] = f2bf(v);
            }
        }
    }
}

// ---------------------------------------------------------------------------

extern "C" void kernel_launch(void* const* d_in, const int* in_sizes, int n_in,
                              void* d_out, int out_size, void* d_ws, size_t ws_size,
                              hipStream_t stream)
{
    const float* x      = (const float*)d_in[0];
    const int*   ei     = (const int*)d_in[1];
    const float* alpha  = (const float*)d_in[2];
    const float* W0     = (const float*)d_in[3];
    const float* b0     = (const float*)d_in[4];
    const float* W1     = (const float*)d_in[5];
    const float* R1     = (const float*)d_in[6];
    const float* b1     = (const float*)d_in[7];
    const float* W2     = (const float*)d_in[8];
    const float* R2     = (const float*)d_in[9];
    const float* b2     = (const float*)d_in[10];
    const float* W3     = (const float*)d_in[11];
    const float* b3     = (const float*)d_in[12];
    const float* W4     = (const float*)d_in[13];
    const float* R4     = (const float*)d_in[14];
    const float* b4     = (const float*)d_in[15];

    const int N = in_sizes[0] / 128;
    const int E = in_sizes[1] / 2;
    const int* row = ei;
    const int* col = ei + E;

    size_t off = 0;
    auto alloc = [&](size_t bytes) -> void* {
        void* p = (char*)d_ws + off;
        off += (bytes + 255) & ~(size_t)255;
        return p;
    };
    int*   deg    = (int*)alloc((size_t)N * 4);
    int*   rp     = (int*)alloc((size_t)(N + 1) * 4);
    int*   cursor = (int*)alloc((size_t)N * 4);
    int*   colS   = (int*)alloc((size_t)E * 4);
    int*   bsum   = (int*)alloc((size_t)64 * 4);
    float* dinv   = (float*)alloc((size_t)N * 4);
    float* cinv   = (float*)alloc((size_t)N * 4);
    unsigned short* Wt0 = (unsigned short*)alloc((size_t)128 * 128 * 2);
    unsigned short* Wt1 = (unsigned short*)alloc((size_t)256 * 256 * 2);
    unsigned short* Wt2 = (unsigned short*)alloc((size_t)256 * 512 * 2);
    unsigned short* Wt3 = (unsigned short*)alloc((size_t)256 * 256 * 2);
    unsigned short* Wt4 = (unsigned short*)alloc((size_t)128 * 512 * 2);
    unsigned short* Xb  = (unsigned short*)alloc((size_t)N * 128 * 2);
    unsigned short* Gb  = (unsigned short*)alloc((size_t)N * 256 * 2);
    unsigned short* Pb  = (unsigned short*)alloc((size_t)N * 256 * 2);
    unsigned short* Ab  = (unsigned short*)alloc((size_t)N * 256 * 2);
    unsigned short* Hb  = Xb;  // alias: Xb only read by L0 agg before Hb written
    (void)ws_size;

    // ---- CSR build ----
    const int SB = (N + 2047) / 2048;  // scan blocks (<=64)
    zero_int_kernel<<<(N + 255) / 256, 256, 0, stream>>>(deg, N);
    count_deg_kernel<<<(E + 255) / 256, 256, 0, stream>>>(row, deg, E);
    scan_p1_kernel<<<SB, 1024, 0, stream>>>(deg, rp, bsum, N);
    scan_p2_kernel<<<1, 64, 0, stream>>>(bsum, SB);
    scan_p3_kernel<<<SB, 1024, 0, stream>>>(deg, rp, cursor, bsum, dinv, cinv, N);
    fill_csr_kernel<<<(E + 255) / 256, 256, 0, stream>>>(row, col, cursor, colS, E);

    // ---- prep ----
    f32_to_bf16_kernel<<<(N * 32 + 255) / 256, 256, 0, stream>>>(x, Xb, N * 32);
    prep_w_kernel<<<(128 * 128 + 255) / 256, 256, 0, stream>>>(W0, 128, nullptr, 0, 128, 128, Wt0);
    prep_w_kernel<<<(256 * 256 + 255) / 256, 256, 0, stream>>>(W1, 128, R1, 128, 256, 256, Wt1);
    prep_w_kernel<<<(256 * 512 + 255) / 256, 256, 0, stream>>>(W2, 256, R2, 256, 256, 256, Wt2);
    prep_w_kernel<<<(256 * 256 + 255) / 256, 256, 0, stream>>>(W3, 256, nullptr, 0, 256, 256, Wt3);
    prep_w_kernel<<<(128 * 512 + 255) / 256, 256, 0, stream>>>(W4, 256, R4, 256, 112, 128, Wt4);

    dim3 aggGrid((N + 3) / 4);
    dim3 g1((N + 127) / 128, 1), g2((N + 127) / 128, 2);

    // ---- L0 (GCN): Hb = bf16( x + a0*(gcn_agg(x)@W0 + b0) ) ----
    agg_bf16_kernel<128, true><<<aggGrid, 256, 0, stream>>>(Xb, 128, rp, colS, dinv, dinv, Ab, 128, N);
    mfma_gemm_kernel<2, false, false, true><<<g1, 256, 0, stream>>>(
        Ab, 128, 128, nullptr, 0, 0, Wt0, b0, x, 128, alpha, 0,
        nullptr, Hb, 128, N, 128);

    // ---- L1 (SAGE 128->256): Gb = relu([mean(Hb)|Hb]@[W1;R1]+b1) ----
    agg_bf16_kernel<128, false><<<aggGrid, 256, 0, stream>>>(Hb, 128, rp, colS, nullptr, cinv, Ab, 128, N);
    mfma_gemm_kernel<1, false, false, true><<<g2, 256, 0, stream>>>(
        Ab, 128, 128, Hb, 128, 128, Wt1, b1, nullptr, 0, nullptr, 0,
        nullptr, Gb, 256, N, 256);

    // ---- L2 (SAGE 256->256): Pb = relu([mean(Gb)|Gb]@[W2;R2]+b2) ----
    agg_bf16_kernel<256, false><<<aggGrid, 256, 0, stream>>>(Gb, 256, rp, colS, nullptr, cinv, Ab, 256, N);
    mfma_gemm_kernel<1, false, false, true><<<g2, 256, 0, stream>>>(
        Ab, 256, 256, Gb, 256, 256, Wt2, b2, nullptr, 0, nullptr, 0,
        nullptr, Pb, 256, N, 256);

    // ---- L3 (GCN): Gb = Pb + a3*(gcn_agg(Pb)@W3 + b3) ----
    agg_bf16_kernel<256, true><<<aggGrid, 256, 0, stream>>>(Pb, 256, rp, colS, dinv, dinv, Ab, 256, N);
    mfma_gemm_kernel<2, true, false, true><<<g2, 256, 0, stream>>>(
        Ab, 256, 256, nullptr, 0, 0, Wt3, b3, Pb, 256, alpha, 3,
        nullptr, Gb, 256, N, 256);

    // ---- L4 (SAGE 256->112): d_out = [mean(Gb)|Gb]@[W4;R4]+b4 (fp32) ----
    agg_bf16_kernel<256, false><<<aggGrid, 256, 0, stream>>>(Gb, 256, rp, colS, nullptr, cinv, Ab, 256, N);
    mfma_gemm_kernel<0, false, true, false><<<g1, 256, 0, stream>>>(
        Ab, 256, 256, Gb, 256, 256, Wt4, b4, nullptr, 0, nullptr, 0,
        (float*)d_out, nullptr, 112, N, 112);
}

// Round 6
// 774.666 us; speedup vs baseline: 2.4372x; 1.0090x over previous
//
#include <hip/hip_runtime.h>

// ---------------------------------------------------------------------------
// SAGE_Re GNN forward, R6.
// - GEMM: double-buffered LDS (2x8KB x A/B), ONE barrier per K-chunk;
//   prefetch chunk k+1 via global_load_lds overlaps chunk k's MFMA phase.
// - agg: 4 gathers in flight for both C=128 and C=256.
// - CSR: 3-phase multi-block scan (R5).
// ---------------------------------------------------------------------------

typedef __attribute__((ext_vector_type(8))) short bf16x8;
typedef __attribute__((ext_vector_type(4))) float f32x4;

__device__ __forceinline__ float bf2f(unsigned short u) {
    union { unsigned int i; float f; } v; v.i = ((unsigned int)u) << 16; return v.f;
}
__device__ __forceinline__ unsigned short f2bf(float f) {
    union { float f; unsigned int i; } v; v.f = f;
    unsigned int r = (v.i + 0x7fffu + ((v.i >> 16) & 1u)) >> 16;
    return (unsigned short)r;
}

// ---------------- CSR build ----------------

__global__ __launch_bounds__(256) void zero_int_kernel(int* __restrict__ p, int n)
{
    int i = blockIdx.x * 256 + threadIdx.x;
    if (i < n) p[i] = 0;
}

__global__ __launch_bounds__(256) void count_deg_kernel(
    const int* __restrict__ row, int* __restrict__ deg, int E)
{
    int e = blockIdx.x * 256 + threadIdx.x;
    if (e < E) atomicAdd(&deg[row[e]], 1);
}

__global__ __launch_bounds__(1024) void scan_p1_kernel(
    const int* __restrict__ deg, int* __restrict__ rp,
    int* __restrict__ bsum, int n)
{
    __shared__ int wsum[16];
    int t = threadIdx.x, lane = t & 63, w = t >> 6;
    int base = blockIdx.x * 2048;
    int carry = 0;
    #pragma unroll
    for (int half = 0; half < 2; ++half) {
        int i = base + half * 1024 + t;
        int xv = (i < n) ? deg[i] : 0;
        int s = xv;
        #pragma unroll
        for (int off = 1; off < 64; off <<= 1) {
            int v = __shfl_up(s, off, 64);
            if (lane >= off) s += v;
        }
        if (lane == 63) wsum[w] = s;
        __syncthreads();
        if (w == 0 && lane < 16) {
            int ws = wsum[lane];
            #pragma unroll
            for (int off = 1; off < 16; off <<= 1) {
                int v = __shfl_up(ws, off, 64);
                if (lane >= off) ws += v;
            }
            wsum[lane] = ws;
        }
        __syncthreads();
        int wo = (w == 0) ? 0 : wsum[w - 1];
        if (i < n) rp[i + 1] = carry + wo + s;
        carry += wsum[15];
        if (half == 0) __syncthreads();
    }
    if (t == 0) bsum[blockIdx.x] = carry;
}

__global__ __launch_bounds__(64) void scan_p2_kernel(int* __restrict__ bsum, int B)
{
    int lane = threadIdx.x;
    int v = (lane < B) ? bsum[lane] : 0;
    int s = v;
    #pragma unroll
    for (int off = 1; off < 64; off <<= 1) {
        int u = __shfl_up(s, off, 64);
        if (lane >= off) s += u;
    }
    if (lane < B) bsum[lane] = s - v;
}

__global__ __launch_bounds__(1024) void scan_p3_kernel(
    const int* __restrict__ deg, int* __restrict__ rp,
    int* __restrict__ cursor, const int* __restrict__ bsum,
    float* __restrict__ dinv, float* __restrict__ cinv, int n)
{
    int boff = bsum[blockIdx.x];
    int base = blockIdx.x * 2048;
    #pragma unroll
    for (int half = 0; half < 2; ++half) {
        int i = base + half * 1024 + threadIdx.x;
        if (i < n) {
            int d = deg[i];
            int incl = rp[i + 1] + boff;
            rp[i + 1] = incl;
            cursor[i] = incl - d;
            float df = (float)d;
            dinv[i] = (d > 0) ? rsqrtf(df) : 0.0f;
            cinv[i] = 1.0f / fmaxf(df, 1.0f);
        }
    }
    if (blockIdx.x == 0 && threadIdx.x == 0) rp[0] = 0;
}

__global__ __launch_bounds__(256) void fill_csr_kernel(
    const int* __restrict__ row, const int* __restrict__ col,
    int* __restrict__ cursor, int* __restrict__ colS, int E)
{
    int e = blockIdx.x * 256 + threadIdx.x;
    if (e < E) {
        int p = atomicAdd(&cursor[row[e]], 1);
        colS[p] = col[e];
    }
}

// ---------------- prep ----------------

__global__ __launch_bounds__(256) void f32_to_bf16_kernel(
    const float* __restrict__ src, unsigned short* __restrict__ dst, int n4)
{
    int i = blockIdx.x * 256 + threadIdx.x;
    if (i >= n4) return;
    float4 v = ((const float4*)src)[i];
    ushort4 o;
    o.x = f2bf(v.x); o.y = f2bf(v.y); o.z = f2bf(v.z); o.w = f2bf(v.w);
    ((ushort4*)dst)[i] = o;
}

__global__ __launch_bounds__(256) void prep_w_kernel(
    const float* __restrict__ S1, int K1,
    const float* __restrict__ S2, int K2,
    int Nout, int Npad, unsigned short* __restrict__ dst)
{
    int Ktot = K1 + K2;
    int idx = blockIdx.x * 256 + threadIdx.x;
    if (idx >= Npad * Ktot) return;
    int n = idx / Ktot, k = idx - n * Ktot;
    float v = 0.0f;
    if (n < Nout)
        v = (k < K1) ? S1[(size_t)k * Nout + n] : S2[(size_t)(k - K1) * Nout + n];
    dst[idx] = f2bf(v);
}

// ---------------- aggregation: wave per node, multi-edge lanes ----------------

__device__ __forceinline__ void acc8(float* acc, uint4 u, float s) {
    unsigned int xs[4] = {u.x, u.y, u.z, u.w};
    #pragma unroll
    for (int p = 0; p < 4; ++p) {
        union { unsigned int i; float f; } lo, hi;
        lo.i = xs[p] << 16;
        hi.i = xs[p] & 0xffff0000u;
        acc[2 * p]     += s * lo.f;
        acc[2 * p + 1] += s * hi.f;
    }
}

template <int C, bool HAS_ES>
__global__ __launch_bounds__(256) void agg_bf16_kernel(
    const unsigned short* __restrict__ h, int ldh,
    const int* __restrict__ rp, const int* __restrict__ cols,
    const float* __restrict__ escale, const float* __restrict__ nscale,
    unsigned short* __restrict__ out, int ldo, int n)
{
    constexpr int LPE = (C == 256) ? 32 : 16;  // lanes per edge
    constexpr int EPG = 64 / LPE;              // edges per group (2 or 4)
    constexpr int UNR = 4;                     // gathers in flight per lane
    int node = blockIdx.x * 4 + (threadIdx.x >> 6);
    if (node >= n) return;
    int lane = threadIdx.x & 63;
    int grp = lane / LPE, sub = lane % LPE;
    const unsigned short* hc = h + sub * 8;

    int s = rp[node], e = rp[node + 1];
    float acc[8];
    #pragma unroll
    for (int k = 0; k < 8; ++k) acc[k] = 0.0f;

    for (int i = s; i < e; i += UNR * EPG) {
        int cc[UNR]; float sc[UNR]; uint4 uu[UNR];
        #pragma unroll
        for (int u = 0; u < UNR; ++u) {
            int ii = i + u * EPG + grp;
            bool valid = ii < e;
            int c = valid ? cols[ii] : 0;
            cc[u] = c;
            sc[u] = valid ? (HAS_ES ? escale[c] : 1.0f) : 0.0f;
        }
        #pragma unroll
        for (int u = 0; u < UNR; ++u)
            uu[u] = *(const uint4*)(hc + (size_t)cc[u] * ldh);
        #pragma unroll
        for (int u = 0; u < UNR; ++u)
            acc8(acc, uu[u], sc[u]);
    }

    #pragma unroll
    for (int k = 0; k < 8; ++k) {
        if (EPG == 4) acc[k] += __shfl_xor(acc[k], 16, 64);
        acc[k] += __shfl_xor(acc[k], 32, 64);
    }

    if (grp == 0) {
        float ns = nscale[node];
        uint4 o;
        unsigned int* op = (unsigned int*)&o;
        #pragma unroll
        for (int p = 0; p < 4; ++p) {
            unsigned short a = f2bf(acc[2 * p] * ns);
            unsigned short b = f2bf(acc[2 * p + 1] * ns);
            op[p] = (unsigned int)a | ((unsigned int)b << 16);
        }
        *(uint4*)(out + (size_t)node * ldo + sub * 8) = o;
    }
}

// ---------------- bf16 MFMA GEMM, 128x128 tile, double-buffered -------------
// One barrier per chunk: barrier -> issue k+1 into buf p^1 -> compute buf p.
// At the barrier, only chunk-k loads are outstanding (full compute-phase old).

__device__ __forceinline__ void g2l16(const unsigned short* g, unsigned short* l) {
    __builtin_amdgcn_global_load_lds(
        (const __attribute__((address_space(1))) unsigned int*)g,
        (__attribute__((address_space(3))) unsigned int*)l, 16, 0, 0);
}

template <int EPI, bool RES_BF16, bool WF32, bool WB16>
__global__ __launch_bounds__(256) void mfma_gemm_kernel(
    const unsigned short* __restrict__ A1, int K1, int lda1,
    const unsigned short* __restrict__ A2, int K2, int lda2,
    const unsigned short* __restrict__ Bt,
    const float* __restrict__ bias,
    const void* __restrict__ res, int ldres,
    const float* __restrict__ alpha_ptr, int alpha_idx,
    float* __restrict__ outf, unsigned short* __restrict__ outb, int ldo,
    int M, int Nout)
{
    __shared__ unsigned short As[2][128 * 32];
    __shared__ unsigned short Bs[2][128 * 32];
    int t = threadIdx.x;
    int m0 = blockIdx.x * 128, n0 = blockIdx.y * 128;
    int Ktot = K1 + K2;
    int w = t >> 6, lane = t & 63;
    int wm = w & 1, wn = w >> 1;
    int q = lane >> 4, l16 = lane & 15;

    int roff = t >> 2;
    int koff = (t & 3) * 8;

    int gmA0 = m0 + roff;       if (gmA0 >= M) gmA0 = M - 1;
    int gmA1 = m0 + 64 + roff;  if (gmA1 >= M) gmA1 = M - 1;
    int gnB0 = n0 + roff;
    int gnB1 = n0 + 64 + roff;

    const size_t a0off = (size_t)gmA0, a1off = (size_t)gmA1;

    f32x4 acc[4][4];
    #pragma unroll
    for (int i = 0; i < 4; ++i)
        #pragma unroll
        for (int j = 0; j < 4; ++j)
            #pragma unroll
            for (int r = 0; r < 4; ++r) acc[i][j][r] = 0.0f;

    const int KC = Ktot >> 5;

    auto issue = [&](int kc, int p) {
        int k0 = kc * 32;
        const unsigned short* Ap; int lda, kk;
        if (k0 < K1) { Ap = A1; lda = lda1; kk = k0; }
        else         { Ap = A2; lda = lda2; kk = k0 - K1; }
        g2l16(Ap + a0off * lda + kk + koff, &As[p][w * 512]);
        g2l16(Ap + a1off * lda + kk + koff, &As[p][2048 + w * 512]);
        g2l16(Bt + (size_t)gnB0 * Ktot + k0 + koff, &Bs[p][w * 512]);
        g2l16(Bt + (size_t)gnB1 * Ktot + k0 + koff, &Bs[p][2048 + w * 512]);
    };

    issue(0, 0);
    for (int kc = 0; kc < KC; ++kc) {
        int p = kc & 1;
        __syncthreads();                    // drains chunk-kc loads; protects buf p^1
        if (kc + 1 < KC) issue(kc + 1, p ^ 1);
        bf16x8 af[4], bfr[4];
        #pragma unroll
        for (int i = 0; i < 4; ++i)
            af[i] = *(const bf16x8*)&As[p][(wm * 64 + i * 16 + l16) * 32 + q * 8];
        #pragma unroll
        for (int j = 0; j < 4; ++j)
            bfr[j] = *(const bf16x8*)&Bs[p][(wn * 64 + j * 16 + l16) * 32 + q * 8];
        #pragma unroll
        for (int i = 0; i < 4; ++i)
            #pragma unroll
            for (int j = 0; j < 4; ++j)
                acc[i][j] = __builtin_amdgcn_mfma_f32_16x16x32_bf16(
                    af[i], bfr[j], acc[i][j], 0, 0, 0);
    }

    float alpha = 0.0f;
    if (EPI == 2) alpha = alpha_ptr[alpha_idx];
    #pragma unroll
    for (int i = 0; i < 4; ++i) {
        #pragma unroll
        for (int j = 0; j < 4; ++j) {
            int n = n0 + wn * 64 + j * 16 + l16;
            if (n >= Nout) continue;
            float bv = bias[n];
            #pragma unroll
            for (int r = 0; r < 4; ++r) {
                int m = m0 + wm * 64 + i * 16 + q * 4 + r;
                if (m >= M) continue;
                float v = acc[i][j][r] + bv;
                if (EPI == 1) v = fmaxf(v, 0.0f);
                if (EPI == 2) {
                    float r0 = RES_BF16
                        ? bf2f(((const unsigned short*)res)[(size_t)m * ldres + n])
                        : ((const float*)res)[(size_t)m * ldres + n];
                    v = r0 + alpha * v;
                }
                if (WF32) outf[(size_t)m * ldo + n] = v;
                if (WB16) outb[(size_t)m * ldo + n] = f2bf(v);
            }
        }
    }
}

// ---------------------------------------------------------------------------

extern "C" void kernel_launch(void* const* d_in, const int* in_sizes, int n_in,
                              void* d_out, int out_size, void* d_ws, size_t ws_size,
                              hipStream_t stream)
{
    const float* x      = (const float*)d_in[0];
    const int*   ei     = (const int*)d_in[1];
    const float* alpha  = (const float*)d_in[2];
    const float* W0     = (const float*)d_in[3];
    const float* b0     = (const float*)d_in[4];
    const float* W1     = (const float*)d_in[5];
    const float* R1     = (const float*)d_in[6];
    const float* b1     = (const float*)d_in[7];
    const float* W2     = (const float*)d_in[8];
    const float* R2     = (const float*)d_in[9];
    const float* b2     = (const float*)d_in[10];
    const float* W3     = (const float*)d_in[11];
    const float* b3     = (const float*)d_in[12];
    const float* W4     = (const float*)d_in[13];
    const float* R4     = (const float*)d_in[14];
    const float* b4     = (const float*)d_in[15];

    const int N = in_sizes[0] / 128;
    const int E = in_sizes[1] / 2;
    const int* row = ei;
    const int* col = ei + E;

    size_t off = 0;
    auto alloc = [&](size_t bytes) -> void* {
        void* p = (char*)d_ws + off;
        off += (bytes + 255) & ~(size_t)255;
        return p;
    };
    int*   deg    = (int*)alloc((size_t)N * 4);
    int*   rp     = (int*)alloc((size_t)(N + 1) * 4);
    int*   cursor = (int*)alloc((size_t)N * 4);
    int*   colS   = (int*)alloc((size_t)E * 4);
    int*   bsum   = (int*)alloc((size_t)64 * 4);
    float* dinv   = (float*)alloc((size_t)N * 4);
    float* cinv   = (float*)alloc((size_t)N * 4);
    unsigned short* Wt0 = (unsigned short*)alloc((size_t)128 * 128 * 2);
    unsigned short* Wt1 = (unsigned short*)alloc((size_t)256 * 256 * 2);
    unsigned short* Wt2 = (unsigned short*)alloc((size_t)256 * 512 * 2);
    unsigned short* Wt3 = (unsigned short*)alloc((size_t)256 * 256 * 2);
    unsigned short* Wt4 = (unsigned short*)alloc((size_t)128 * 512 * 2);
    unsigned short* Xb  = (unsigned short*)alloc((size_t)N * 128 * 2);
    unsigned short* Gb  = (unsigned short*)alloc((size_t)N * 256 * 2);
    unsigned short* Pb  = (unsigned short*)alloc((size_t)N * 256 * 2);
    unsigned short* Ab  = (unsigned short*)alloc((size_t)N * 256 * 2);
    unsigned short* Hb  = Xb;  // alias: Xb only read by L0 agg before Hb written
    (void)ws_size;

    // ---- CSR build ----
    const int SB = (N + 2047) / 2048;
    zero_int_kernel<<<(N + 255) / 256, 256, 0, stream>>>(deg, N);
    count_deg_kernel<<<(E + 255) / 256, 256, 0, stream>>>(row, deg, E);
    scan_p1_kernel<<<SB, 1024, 0, stream>>>(deg, rp, bsum, N);
    scan_p2_kernel<<<1, 64, 0, stream>>>(bsum, SB);
    scan_p3_kernel<<<SB, 1024, 0, stream>>>(deg, rp, cursor, bsum, dinv, cinv, N);
    fill_csr_kernel<<<(E + 255) / 256, 256, 0, stream>>>(row, col, cursor, colS, E);

    // ---- prep ----
    f32_to_bf16_kernel<<<(N * 32 + 255) / 256, 256, 0, stream>>>(x, Xb, N * 32);
    prep_w_kernel<<<(128 * 128 + 255) / 256, 256, 0, stream>>>(W0, 128, nullptr, 0, 128, 128, Wt0);
    prep_w_kernel<<<(256 * 256 + 255) / 256, 256, 0, stream>>>(W1, 128, R1, 128, 256, 256, Wt1);
    prep_w_kernel<<<(256 * 512 + 255) / 256, 256, 0, stream>>>(W2, 256, R2, 256, 256, 256, Wt2);
    prep_w_kernel<<<(256 * 256 + 255) / 256, 256, 0, stream>>>(W3, 256, nullptr, 0, 256, 256, Wt3);
    prep_w_kernel<<<(128 * 512 + 255) / 256, 256, 0, stream>>>(W4, 256, R4, 256, 112, 128, Wt4);

    dim3 aggGrid((N + 3) / 4);
    dim3 g1((N + 127) / 128, 1), g2((N + 127) / 128, 2);

    // ---- L0 (GCN): Hb = bf16( x + a0*(gcn_agg(x)@W0 + b0) ) ----
    agg_bf16_kernel<128, true><<<aggGrid, 256, 0, stream>>>(Xb, 128, rp, colS, dinv, dinv, Ab, 128, N);
    mfma_gemm_kernel<2, false, false, true><<<g1, 256, 0, stream>>>(
        Ab, 128, 128, nullptr, 0, 0, Wt0, b0, x, 128, alpha, 0,
        nullptr, Hb, 128, N, 128);

    // ---- L1 (SAGE 128->256): Gb = relu([mean(Hb)|Hb]@[W1;R1]+b1) ----
    agg_bf16_kernel<128, false><<<aggGrid, 256, 0, stream>>>(Hb, 128, rp, colS, nullptr, cinv, Ab, 128, N);
    mfma_gemm_kernel<1, false, false, true><<<g2, 256, 0, stream>>>(
        Ab, 128, 128, Hb, 128, 128, Wt1, b1, nullptr, 0, nullptr, 0,
        nullptr, Gb, 256, N, 256);

    // ---- L2 (SAGE 256->256): Pb = relu([mean(Gb)|Gb]@[W2;R2]+b2) ----
    agg_bf16_kernel<256, false><<<aggGrid, 256, 0, stream>>>(Gb, 256, rp, colS, nullptr, cinv, Ab, 256, N);
    mfma_gemm_kernel<1, false, false, true><<<g2, 256, 0, stream>>>(
        Ab, 256, 256, Gb, 256, 256, Wt2, b2, nullptr, 0, nullptr, 0,
        nullptr, Pb, 256, N, 256);

    // ---- L3 (GCN): Gb = Pb + a3*(gcn_agg(Pb)@W3 + b3) ----
    agg_bf16_kernel<256, true><<<aggGrid, 256, 0, stream>>>(Pb, 256, rp, colS, dinv, dinv, Ab, 256, N);
    mfma_gemm_kernel<2, true, false, true><<<g2, 256, 0, stream>>>(
        Ab, 256, 256, nullptr, 0, 0, Wt3, b3, Pb, 256, alpha, 3,
        nullptr, Gb, 256, N, 256);

    // ---- L4 (SAGE 256->112): d_out = [mean(Gb)|Gb]@[W4;R4]+b4 (fp32) ----
    agg_bf16_kernel<256, false><<<aggGrid, 256, 0, stream>>>(Gb, 256, rp, colS, nullptr, cinv, Ab, 256, N);
    mfma_gemm_kernel<0, false, true, false><<<g1, 256, 0, stream>>>(
        Ab, 256, 256, Gb, 256, 256, Wt4, b4, nullptr, 0, nullptr, 0,
        (float*)d_out, nullptr, 112, N, 112);
}